// Round 5
// baseline (231.301 us; speedup 1.0000x reference)
//
#include <hip/hip_runtime.h>

// ---------------------------------------------------------------------------
// MultiHeadedAttention: B=2, S=2048, Dm=1024, H=16, hd=64
// R8 = R7 resubmit (container infra failure, kernel re-audited: no hang
// hazard, barriers uniform, bounds OK).
// R7: 32x32x16 MFMA attention + split-K:
//  - wave owns 32 q-rows; S^T = mfma_32x32x16(K, Q): lane holds P for ONE
//    q-column -> P->PV B-frag needs only a lane<->lane+32 half exchange
//    (8 shfl_xor per 64-key tile vs 32 ds_bpermute per 32 rows before)
//  - LDS fragment reads per q-row HALVED (16 ds_read_b128 per 32 rows)
//  - split-K: wave pairs (ks=0/1) take even/odd key tiles; O/lsum are linear
//    (max-free softmax) -> combined once at the end via LDS. 512-thr blocks,
//    8 waves = 4 qsubs x 2 ks, grid (16,NH,B) -> 16 waves/CU
//  - staging/double-buffer identical to R4 (verified); scale pre-folded W_in
// ---------------------------------------------------------------------------

typedef __bf16 bf16x8 __attribute__((ext_vector_type(8)));
typedef float f32x4 __attribute__((ext_vector_type(4)));
typedef float f32x16 __attribute__((ext_vector_type(16)));
typedef int i32x4 __attribute__((ext_vector_type(4)));

#define B_   2
#define S_   2048
#define DM   1024
#define NH   16
#define HD   64
#define N3   3072
#define M_   4096   // B_*S_

// 0.125 (1/sqrt(64)) * log2(e) -- folded into W_in Q-columns on host side
#define SCALE_LOG2E 0.180336884f

__device__ __forceinline__ unsigned short f2bf(float f) {
  unsigned int u = __float_as_uint(f);
  u += 0x7fffu + ((u >> 16) & 1u);   // round-to-nearest-even
  return (unsigned short)(u >> 16);
}

__device__ __forceinline__ void gload_lds16(void* lds, const void* g) {
  __builtin_amdgcn_global_load_lds(
      (__attribute__((address_space(1))) void*)g,
      (__attribute__((address_space(3))) void*)lds, 16, 0, 0);
}

// ---------------- fp32 -> bf16 elementwise (query) -------------------------
__global__ __launch_bounds__(256) void f32_to_bf16_vec(
    const float4* __restrict__ in, unsigned short* __restrict__ out, int n4) {
  int i = blockIdx.x * 256 + threadIdx.x;
  if (i < n4) {
    float4 v = in[i];
    ushort4 o;
    o.x = f2bf(v.x); o.y = f2bf(v.y); o.z = f2bf(v.z); o.w = f2bf(v.w);
    *(ushort4*)(&out[(size_t)i * 4]) = o;
  }
}

// ------- fp32 [R][C] -> bf16 [C][R] transpose (weights), row-scaled --------
__global__ __launch_bounds__(256) void transpose_f32_bf16(
    const float* __restrict__ in, unsigned short* __restrict__ out, int R, int C,
    int scale_rows, float scale) {
  __shared__ float tile[32][33];
  const int tx = threadIdx.x, ty = threadIdx.y;
  const int x = blockIdx.x * 32 + tx;
  const int y0 = blockIdx.y * 32;
#pragma unroll
  for (int j = 0; j < 32; j += 8)
    tile[ty + j][tx] = in[(size_t)(y0 + ty + j) * C + x];
  __syncthreads();
  const int ox = y0 + tx;
  const int oy0 = blockIdx.x * 32;
#pragma unroll
  for (int j = 0; j < 32; j += 8) {
    const int orow = oy0 + ty + j;
    float v = tile[tx][ty + j];
    if (orow < scale_rows) v *= scale;
    out[(size_t)orow * R + ox] = f2bf(v);
  }
}

// ---------------- V slice of qkv -> vT[b][h][d][s] (bf16) ------------------
__global__ __launch_bounds__(256) void transpose_v(
    const unsigned short* __restrict__ qkv, unsigned short* __restrict__ vT) {
  __shared__ unsigned short tile[32][33];
  const int tx = threadIdx.x, ty = threadIdx.y;
  const int c0 = blockIdx.x * 32;   // v-dim 0..1023
  const int r0 = blockIdx.y * 32;   // token 0..4095
#pragma unroll
  for (int j = 0; j < 32; j += 8)
    tile[ty + j][tx] = qkv[(size_t)(r0 + ty + j) * N3 + 2 * DM + c0 + tx];
  __syncthreads();
  const int b = r0 >> 11;
  const int srow = (r0 & 2047);
  const int head = c0 >> 6;
#pragma unroll
  for (int j = 0; j < 32; j += 8) {
    const int d = (c0 & 63) + ty + j;
    vT[(size_t)((b * NH + head) * HD + d) * S_ + srow + tx] = tile[tx][ty + j];
  }
}

// ---------------- GEMM: C[M][N] = A[M][K] @ Bt[N][K]^T ---------------------
template <int OUT_BF16>
__global__ __launch_bounds__(256) void gemm_abt(
    const unsigned short* __restrict__ A, const unsigned short* __restrict__ Bt,
    void* __restrict__ Cv, int M, int N, int K) {
  __shared__ __align__(16) unsigned short a_sm[128 * 32];
  __shared__ __align__(16) unsigned short b_sm[128 * 32];
  const int tid = threadIdx.x;
  const int lane = tid & 63, wave = tid >> 6;
  const int quad = lane >> 4, l15 = lane & 15;
  const int row0 = blockIdx.y * 128, col0 = blockIdx.x * 128;
  const int wm = (wave >> 1) * 64, wn = (wave & 1) * 64;

  f32x4 acc[4][4];
#pragma unroll
  for (int i = 0; i < 4; i++)
#pragma unroll
    for (int j = 0; j < 4; j++) acc[i][j] = (f32x4){0.f, 0.f, 0.f, 0.f};

  const int e0 = tid * 8;

  for (int k0 = 0; k0 < K; k0 += 32) {
    __syncthreads();
#pragma unroll
    for (int i = 0; i < 2; i++) {
      int e = e0 + i * 2048;
      int r = e >> 5, c = e & 31;
      gload_lds16(&a_sm[e], &A[(size_t)(row0 + r) * K + k0 + c]);
      gload_lds16(&b_sm[e], &Bt[(size_t)(col0 + r) * K + k0 + c]);
    }
    __syncthreads();

    bf16x8 af[4], bfb[4];
#pragma unroll
    for (int i = 0; i < 4; i++) {
      af[i]  = *(const bf16x8*)&a_sm[(wm + i * 16 + l15) * 32 + quad * 8];
      bfb[i] = *(const bf16x8*)&b_sm[(wn + i * 16 + l15) * 32 + quad * 8];
    }
#pragma unroll
    for (int i = 0; i < 4; i++)
#pragma unroll
      for (int j = 0; j < 4; j++)
        acc[i][j] = __builtin_amdgcn_mfma_f32_16x16x32_bf16(af[i], bfb[j], acc[i][j], 0, 0, 0);
  }

#pragma unroll
  for (int i = 0; i < 4; i++) {
#pragma unroll
    for (int j = 0; j < 4; j++) {
#pragma unroll
      for (int r = 0; r < 4; r++) {
        const int row = row0 + wm + i * 16 + quad * 4 + r;
        const int col = col0 + wn + j * 16 + l15;
        const float v = acc[i][j][r];
        if (OUT_BF16)
          ((unsigned short*)Cv)[(size_t)row * N + col] = f2bf(v);
        else
          ((float*)Cv)[(size_t)row * N + col] = v;
      }
    }
  }
}

// ---------------- fused causal attention v7 (32x32 + split-K) --------------
// grid (16, NH, B), 512 threads (8 waves). wave = qsub*2+ks: qsub 0..3 owns
// 32 q-rows (qt*128 + qsub*32); ks=0/1 take even/odd key tiles (split-K).
// S^T = mfma_32x32x16(K, Q): D[m=key][n=q=lane&31]; lane holds 16 keys of
// its q per 32-key block, split across lane-halves (4*(lane>>5) offset).
// PV B-frag = pack own 4-key pairs + one shfl_xor(32) half-exchange.
// O^T = mfma_32x32x16(V^T, P^T). Linear combine of split-K partials at end.
__global__ __launch_bounds__(512, 4) void attn_fused7(
    const unsigned short* __restrict__ qkv,
    const unsigned short* __restrict__ vT,
    unsigned short* __restrict__ attnout) {
  const int h = blockIdx.y, b = blockIdx.z;
  // reverse-pair qt across batch so co-resident blocks balance causal work
  const int qt = (b == 0) ? blockIdx.x : (15 - blockIdx.x);
  const int tid = threadIdx.x;
  const int lane = tid & 63, wave = tid >> 6;   // wave 0..7
  const int qsub = wave >> 1, ks = wave & 1;
  const int l31 = lane & 31, lh = lane >> 5;
  const int swz = l31 & 7;

  __shared__ __align__(16) unsigned short k_sm[2 * 4096];   // [buf][64 keys][64 d]
  __shared__ __align__(16) unsigned short vt_sm[2 * 4096];  // [buf][64 d][64 keys]
  __shared__ float lsum_sm[256];

  const int qbase = qt * 128 + qsub * 32;
  const int qrow = qbase + l31;   // this lane's q row (one q per lane)

  // Q fragments: B[k = c*16 + lh*8 + j][n = l31]
  bf16x8 qf[4];
  {
    const unsigned short* qp = qkv + (size_t)(b * S_ + qrow) * N3 + h * HD + lh * 8;
#pragma unroll
    for (int c = 0; c < 4; c++) qf[c] = *(const bf16x8*)(qp + c * 16);
  }

  f32x16 oacc[2];   // O^T: d = od*32 + (r&3)+8*(r>>2)+4*lh, col = qrow
#pragma unroll
  for (int r = 0; r < 16; r++) { oacc[0][r] = 0.f; oacc[1][r] = 0.f; }
  float lsum = 0.f;

  // staging: thread -> (row r0s, phys chunk tid&7); phys chunk holds logical
  // chunk (tid&7)^(r0s&7)  (XOR swizzle, conflict-free b128 reads)
  const int r0s = tid >> 3;                       // 0..63
  const int gch = ((tid & 7) ^ (r0s & 7)) * 8;
  const unsigned short* kgb = qkv + (size_t)(b * S_ + r0s) * N3 + DM + h * HD + gch;
  const unsigned short* vgb = vT + (size_t)((b * NH + h) * HD + r0s) * S_ + gch;

  const int nt = 2 * qt + 2;
  // prefetch tile 0
  gload_lds16(&k_sm[tid * 8], kgb);
  gload_lds16(&vt_sm[tid * 8], vgb);

  for (int t = 0; t < nt; t++) {
    __syncthreads();   // buf[t&1] staged; buf[(t+1)&1] readers done
    if (t + 1 < nt) {
      const int nb = ((t + 1) & 1) * 4096;
      gload_lds16(&k_sm[nb + tid * 8], kgb + (size_t)(t + 1) * 64 * N3);
      gload_lds16(&vt_sm[nb + tid * 8], vgb + (t + 1) * 64);
    }
    // split-K parity + causal skip
    if (((t ^ ks) & 1) || t * 64 > qbase + 31) continue;

    const unsigned short* kb = &k_sm[(t & 1) * 4096];
    const unsigned short* vb = &vt_sm[(t & 1) * 4096];

    // S^T = K Q^T : two 32x32 outputs (keys t*64+0..31, +32..63)
    f32x16 s0, s1;
#pragma unroll
    for (int r = 0; r < 16; r++) { s0[r] = 0.f; s1[r] = 0.f; }
#pragma unroll
    for (int c = 0; c < 4; c++) {
      const int ch = ((2 * c + lh) ^ swz) * 8;
      bf16x8 kf0 = *(const bf16x8*)&kb[l31 * 64 + ch];
      bf16x8 kf1 = *(const bf16x8*)&kb[(32 + l31) * 64 + ch];
      s0 = __builtin_amdgcn_mfma_f32_32x32x16_bf16(kf0, qf[c], s0, 0, 0, 0);
      s1 = __builtin_amdgcn_mfma_f32_32x32x16_bf16(kf1, qf[c], s1, 0, 0, 0);
    }

    // P = exp2(S) (scale pre-folded); mask only when tile straddles diagonal
    if (t * 64 + 63 <= qbase) {
#pragma unroll
      for (int r = 0; r < 16; r++) { s0[r] = exp2f(s0[r]); s1[r] = exp2f(s1[r]); }
    } else {
      const int kb4 = t * 64 + 4 * lh;
#pragma unroll
      for (int r = 0; r < 16; r++) {
        const int ko = (r & 3) + 8 * (r >> 2);
        const float e0 = exp2f(s0[r]);
        const float e1 = exp2f(s1[r]);
        s0[r] = (kb4 + ko <= qrow) ? e0 : 0.f;
        s1[r] = (kb4 + 32 + ko <= qrow) ? e1 : 0.f;
      }
    }
#pragma unroll
    for (int r = 0; r < 16; r++) lsum += s0[r] + s1[r];

    // O^T += V^T P^T : per (o: 32-key block, c: 16-key chunk) build B-frag.
    // lane holds keys o*32 + {0..3,8..11,16..19,24..27} + 4*lh of its q.
    // lh=0 frag = {own keys c16+0..3, partner keys c16+4..7}
    // lh=1 frag = {partner keys c16+8..11, own keys c16+12..15}
#pragma unroll
    for (int o = 0; o < 2; o++) {
      const f32x16 sv = o ? s1 : s0;
#pragma unroll
      for (int c = 0; c < 2; c++) {
        const int rb = 8 * c;
        const unsigned u0 = __float_as_uint(sv[rb + 0]) + 0x8000u;
        const unsigned u1 = __float_as_uint(sv[rb + 1]) + 0x8000u;
        const unsigned u2 = __float_as_uint(sv[rb + 2]) + 0x8000u;
        const unsigned u3 = __float_as_uint(sv[rb + 3]) + 0x8000u;
        const unsigned u4 = __float_as_uint(sv[rb + 4]) + 0x8000u;
        const unsigned u5 = __float_as_uint(sv[rb + 5]) + 0x8000u;
        const unsigned u6 = __float_as_uint(sv[rb + 6]) + 0x8000u;
        const unsigned u7 = __float_as_uint(sv[rb + 7]) + 0x8000u;
        const int L0 = (int)__builtin_amdgcn_perm(u1, u0, 0x07060302u);
        const int L1 = (int)__builtin_amdgcn_perm(u3, u2, 0x07060302u);
        const int H0 = (int)__builtin_amdgcn_perm(u5, u4, 0x07060302u);
        const int H1 = (int)__builtin_amdgcn_perm(u7, u6, 0x07060302u);
        // lh=0 sends its HI pack, lh=1 sends its LO pack
        const int x0 = lh ? L0 : H0;
        const int x1 = lh ? L1 : H1;
        const int y0 = __shfl_xor(x0, 32);
        const int y1 = __shfl_xor(x1, 32);
        i32x4 bv;
        bv.x = lh ? y0 : L0;
        bv.y = lh ? y1 : L1;
        bv.z = lh ? H0 : y0;
        bv.w = lh ? H1 : y1;
        const bf16x8 pfrag = __builtin_bit_cast(bf16x8, bv);
        const int vch = ((4 * o + 2 * c + lh) ^ swz) * 8;
        bf16x8 vf0 = *(const bf16x8*)&vb[l31 * 64 + vch];
        bf16x8 vf1 = *(const bf16x8*)&vb[(32 + l31) * 64 + vch];
        oacc[0] = __builtin_amdgcn_mfma_f32_32x32x16_bf16(vf0, pfrag, oacc[0], 0, 0, 0);
        oacc[1] = __builtin_amdgcn_mfma_f32_32x32x16_bf16(vf1, pfrag, oacc[1], 0, 0, 0);
      }
    }
  }

  // ---- split-K combine: ks=1 partials -> LDS -> ks=0 adds ----
  __syncthreads();
  float* obuf = ((qsub < 2) ? (float*)k_sm : (float*)vt_sm) + (qsub & 1) * 2048;
  if (ks == 1) {
#pragma unroll
    for (int od = 0; od < 2; od++)
#pragma unroll
      for (int g = 0; g < 4; g++) {
        f32x4 v = {oacc[od][4 * g + 0], oacc[od][4 * g + 1],
                   oacc[od][4 * g + 2], oacc[od][4 * g + 3]};
        *(f32x4*)&obuf[(od * 4 + g) * 256 + lane * 4] = v;
      }
    lsum_sm[qsub * 64 + lane] = lsum;
  }
  __syncthreads();
  if (ks == 1) return;

#pragma unroll
  for (int od = 0; od < 2; od++)
#pragma unroll
    for (int g = 0; g < 4; g++) {
      const f32x4 v = *(const f32x4*)&obuf[(od * 4 + g) * 256 + lane * 4];
#pragma unroll
      for (int r = 0; r < 4; r++) oacc[od][4 * g + r] += v[r];
    }
  lsum += lsum_sm[qsub * 64 + lane];

  // normalize + write: lane's q = qrow; d = od*32 + g*8 + lh*4 + (0..3)
  const float l = lsum + __shfl_xor(lsum, 32);
  const float inv = 1.0f / l;
  const size_t grow = (size_t)(b * S_ + qrow);
#pragma unroll
  for (int od = 0; od < 2; od++)
#pragma unroll
    for (int g = 0; g < 4; g++) {
      ushort4 w;
      w.x = f2bf(oacc[od][4 * g + 0] * inv);
      w.y = f2bf(oacc[od][4 * g + 1] * inv);
      w.z = f2bf(oacc[od][4 * g + 2] * inv);
      w.w = f2bf(oacc[od][4 * g + 3] * inv);
      *(ushort4*)&attnout[grow * DM + h * HD + od * 32 + g * 8 + lh * 4] = w;
    }
}

// ---------------------------------------------------------------------------
extern "C" void kernel_launch(void* const* d_in, const int* in_sizes, int n_in,
                              void* d_out, int out_size, void* d_ws, size_t ws_size,
                              hipStream_t stream) {
  const float* query = (const float*)d_in[0];   // [4096][1024]
  const float* w_in  = (const float*)d_in[1];   // [1024][3072]
  const float* w_out = (const float*)d_in[2];   // [1024][1024]
  float* out = (float*)d_out;                   // [4096][1024] fp32

  char* ws = (char*)d_ws;
  unsigned short* qbf     = (unsigned short*)(ws);                 //  8 MB (dead after gemm1)
  unsigned short* vT      = (unsigned short*)(ws);                 //  8 MB (aliases qbf)
  unsigned short* w_in_t  = (unsigned short*)(ws + 8388608);       //  6 MB [3072][1024]
  unsigned short* w_out_t = (unsigned short*)(ws + 14680064);      //  2 MB [1024][1024]
  unsigned short* qkv     = (unsigned short*)(ws + 16777216);      // 24 MB [4096][3072]
  unsigned short* attn    = (unsigned short*)(ws + 41943040);      //  8 MB [4096][1024]

  // 1. convert query fp32 -> bf16
  f32_to_bf16_vec<<<dim3(M_ * DM / 1024), dim3(256), 0, stream>>>(
      (const float4*)query, qbf, M_ * DM / 4);
  // 2. transpose+convert weights; fold 0.125*log2e into W_in Q-columns
  transpose_f32_bf16<<<dim3(N3 / 32, DM / 32), dim3(32, 8), 0, stream>>>(
      w_in, w_in_t, DM, N3, DM, SCALE_LOG2E);
  transpose_f32_bf16<<<dim3(DM / 32, DM / 32), dim3(32, 8), 0, stream>>>(
      w_out, w_out_t, DM, DM, 0, 1.0f);
  // 3. qkv = query @ W_in   [4096][3072] bf16 (Q slice pre-scaled)
  gemm_abt<1><<<dim3(N3 / 128, M_ / 128), dim3(256), 0, stream>>>(qbf, w_in_t, qkv, M_, N3, DM);
  // 4. vT[b][h][d][s] from qkv V slice (qbf is dead now)
  transpose_v<<<dim3(DM / 32, M_ / 32), dim3(32, 8), 0, stream>>>(qkv, vT);
  // 5. fused causal attention -> attn [4096][1024] bf16
  attn_fused7<<<dim3(16, NH, B_), dim3(512), 0, stream>>>(qkv, vT, attn);
  // 6. out = attn @ W_out   [4096][1024] fp32
  gemm_abt<0><<<dim3(DM / 128, M_ / 128), dim3(256), 0, stream>>>(attn, w_out_t, out, M_, DM, DM);
}

// Round 6
// 208.505 us; speedup vs baseline: 1.1093x; 1.1093x over previous
//
#include <hip/hip_runtime.h>

// ---------------------------------------------------------------------------
// MultiHeadedAttention: B=2, S=2048, Dm=1024, H=16, hd=64
// R9: R4 compute (best verified, 58.8us) + T4 counted-vmcnt staging:
//  - triple-buffered K/V (3x8KB each), prefetch distance 2
//  - raw s_barrier + "s_waitcnt vmcnt(2)" per tile: each wave waits only its
//    OWN tile-t loads; tile-(t+1) loads stay in flight across the barrier
//    (replaces __syncthreads' full vmcnt(0)+lgkmcnt(0) drain -> removes the
//    per-tile staging-drain convoy, the m233-style ~70% overhead signature)
//  - everything else byte-identical to R4: (j,31-j) q-tile pairing, 512 thr,
//    16x16x32 MFMA, ds_bpermute P-transpose, scale*log2e pre-folded in W_in
// ---------------------------------------------------------------------------

typedef __bf16 bf16x8 __attribute__((ext_vector_type(8)));
typedef float f32x4 __attribute__((ext_vector_type(4)));
typedef int i32x4 __attribute__((ext_vector_type(4)));

#define B_   2
#define S_   2048
#define DM   1024
#define NH   16
#define HD   64
#define N3   3072
#define M_   4096   // B_*S_

// 0.125 (1/sqrt(64)) * log2(e) -- folded into W_in Q-columns on host side
#define SCALE_LOG2E 0.180336884f

__device__ __forceinline__ unsigned short f2bf(float f) {
  unsigned int u = __float_as_uint(f);
  u += 0x7fffu + ((u >> 16) & 1u);   // round-to-nearest-even
  return (unsigned short)(u >> 16);
}

__device__ __forceinline__ void gload_lds16(void* lds, const void* g) {
  __builtin_amdgcn_global_load_lds(
      (__attribute__((address_space(1))) void*)g,
      (__attribute__((address_space(3))) void*)lds, 16, 0, 0);
}

// ---------------- fp32 -> bf16 elementwise (query) -------------------------
__global__ __launch_bounds__(256) void f32_to_bf16_vec(
    const float4* __restrict__ in, unsigned short* __restrict__ out, int n4) {
  int i = blockIdx.x * 256 + threadIdx.x;
  if (i < n4) {
    float4 v = in[i];
    ushort4 o;
    o.x = f2bf(v.x); o.y = f2bf(v.y); o.z = f2bf(v.z); o.w = f2bf(v.w);
    *(ushort4*)(&out[(size_t)i * 4]) = o;
  }
}

// ------- fp32 [R][C] -> bf16 [C][R] transpose (weights), row-scaled --------
__global__ __launch_bounds__(256) void transpose_f32_bf16(
    const float* __restrict__ in, unsigned short* __restrict__ out, int R, int C,
    int scale_rows, float scale) {
  __shared__ float tile[32][33];
  const int tx = threadIdx.x, ty = threadIdx.y;
  const int x = blockIdx.x * 32 + tx;
  const int y0 = blockIdx.y * 32;
#pragma unroll
  for (int j = 0; j < 32; j += 8)
    tile[ty + j][tx] = in[(size_t)(y0 + ty + j) * C + x];
  __syncthreads();
  const int ox = y0 + tx;
  const int oy0 = blockIdx.x * 32;
#pragma unroll
  for (int j = 0; j < 32; j += 8) {
    const int orow = oy0 + ty + j;
    float v = tile[tx][ty + j];
    if (orow < scale_rows) v *= scale;
    out[(size_t)orow * R + ox] = f2bf(v);
  }
}

// ---------------- V slice of qkv -> vT[b][h][d][s] (bf16) ------------------
__global__ __launch_bounds__(256) void transpose_v(
    const unsigned short* __restrict__ qkv, unsigned short* __restrict__ vT) {
  __shared__ unsigned short tile[32][33];
  const int tx = threadIdx.x, ty = threadIdx.y;
  const int c0 = blockIdx.x * 32;   // v-dim 0..1023
  const int r0 = blockIdx.y * 32;   // token 0..4095
#pragma unroll
  for (int j = 0; j < 32; j += 8)
    tile[ty + j][tx] = qkv[(size_t)(r0 + ty + j) * N3 + 2 * DM + c0 + tx];
  __syncthreads();
  const int b = r0 >> 11;
  const int srow = (r0 & 2047);
  const int head = c0 >> 6;
#pragma unroll
  for (int j = 0; j < 32; j += 8) {
    const int d = (c0 & 63) + ty + j;
    vT[(size_t)((b * NH + head) * HD + d) * S_ + srow + tx] = tile[tx][ty + j];
  }
}

// ---------------- GEMM: C[M][N] = A[M][K] @ Bt[N][K]^T ---------------------
template <int OUT_BF16>
__global__ __launch_bounds__(256) void gemm_abt(
    const unsigned short* __restrict__ A, const unsigned short* __restrict__ Bt,
    void* __restrict__ Cv, int M, int N, int K) {
  __shared__ __align__(16) unsigned short a_sm[128 * 32];
  __shared__ __align__(16) unsigned short b_sm[128 * 32];
  const int tid = threadIdx.x;
  const int lane = tid & 63, wave = tid >> 6;
  const int quad = lane >> 4, l15 = lane & 15;
  const int row0 = blockIdx.y * 128, col0 = blockIdx.x * 128;
  const int wm = (wave >> 1) * 64, wn = (wave & 1) * 64;

  f32x4 acc[4][4];
#pragma unroll
  for (int i = 0; i < 4; i++)
#pragma unroll
    for (int j = 0; j < 4; j++) acc[i][j] = (f32x4){0.f, 0.f, 0.f, 0.f};

  const int e0 = tid * 8;

  for (int k0 = 0; k0 < K; k0 += 32) {
    __syncthreads();
#pragma unroll
    for (int i = 0; i < 2; i++) {
      int e = e0 + i * 2048;
      int r = e >> 5, c = e & 31;
      gload_lds16(&a_sm[e], &A[(size_t)(row0 + r) * K + k0 + c]);
      gload_lds16(&b_sm[e], &Bt[(size_t)(col0 + r) * K + k0 + c]);
    }
    __syncthreads();

    bf16x8 af[4], bfb[4];
#pragma unroll
    for (int i = 0; i < 4; i++) {
      af[i]  = *(const bf16x8*)&a_sm[(wm + i * 16 + l15) * 32 + quad * 8];
      bfb[i] = *(const bf16x8*)&b_sm[(wn + i * 16 + l15) * 32 + quad * 8];
    }
#pragma unroll
    for (int i = 0; i < 4; i++)
#pragma unroll
      for (int j = 0; j < 4; j++)
        acc[i][j] = __builtin_amdgcn_mfma_f32_16x16x32_bf16(af[i], bfb[j], acc[i][j], 0, 0, 0);
  }

#pragma unroll
  for (int i = 0; i < 4; i++) {
#pragma unroll
    for (int j = 0; j < 4; j++) {
#pragma unroll
      for (int r = 0; r < 4; r++) {
        const int row = row0 + wm + i * 16 + quad * 4 + r;
        const int col = col0 + wn + j * 16 + l15;
        const float v = acc[i][j][r];
        if (OUT_BF16)
          ((unsigned short*)Cv)[(size_t)row * N + col] = f2bf(v);
        else
          ((float*)Cv)[(size_t)row * N + col] = v;
      }
    }
  }
}

// ---------------- fused causal attention v8 --------------------------------
// grid (16, NH, B), 512 threads (8 waves).
// Block j owns q-tiles j (waves 0-3) and 31-j (waves 4-7), 64 rows each.
// Triple-buffered K/V staging, prefetch distance 2, ONE raw s_barrier per
// key-tile with COUNTED vmcnt (no full drain in the loop).
// S^T = mfma(K, Q); O^T = mfma(V^T, P^T) with ds_bpermute P-transpose.
__global__ __launch_bounds__(512, 4) void attn_fused8(
    const unsigned short* __restrict__ qkv,
    const unsigned short* __restrict__ vT,
    unsigned short* __restrict__ attnout) {
  const int h = blockIdx.y, b = blockIdx.z;
  const int j = blockIdx.x;                     // pair index 0..15
  const int tid = threadIdx.x;
  const int lane = tid & 63, wave = tid >> 6;   // wave 0..7
  const int quad = lane >> 4, l15 = lane & 15;
  const int sw = l15 & 7;

  __shared__ __align__(16) unsigned short k_sm[3 * 4096];   // [buf][64 keys][64 d]
  __shared__ __align__(16) unsigned short vt_sm[3 * 4096];  // [buf][64 d][64 keys]

  // wave 0..3 -> low q-tile (rows j*64 ..); wave 4..7 -> high tile ((31-j)*64 ..)
  const int wrow0 = (wave < 4) ? (j * 64 + wave * 16)
                               : ((31 - j) * 64 + (wave - 4) * 16);
  const int qrow = wrow0 + l15;            // this lane's q row (seq-local)

  // Q fragment (B-operand for S^T, A/B layouts are lane-symmetric)
  bf16x8 qf[2];
  {
    const unsigned short* qp = qkv + (size_t)(b * S_ + qrow) * N3 + h * HD + quad * 8;
    qf[0] = *(const bf16x8*)qp;
    qf[1] = *(const bf16x8*)(qp + 32);
  }

  f32x4 o[4];   // O^T accumulator: d = mb*16+quad*4+r, col = qrow
#pragma unroll
  for (int n = 0; n < 4; n++) o[n] = (f32x4){0.f, 0.f, 0.f, 0.f};
  float lsum = 0.f;

  // staging: thread -> (row r0s, phys chunk tid&7); phys chunk holds logical
  // chunk (tid&7)^(r0s&7)  (XOR swizzle, conflict-free b128 reads)
  const int r0s = tid >> 3;                       // 0..63
  const int gch = ((tid & 7) ^ (r0s & 7)) * 8;
  const unsigned short* kgb = qkv + (size_t)(b * S_ + r0s) * N3 + DM + h * HD + gch;
  const unsigned short* vgb = vT + (size_t)((b * NH + h) * HD + r0s) * S_ + gch;

  // bpermute pull addresses (byte addr = src_lane*4), quad-dim transpose
  const int addrA = (((quad * 2) & 3) * 16 + l15) * 4;
  const int addrB = (((quad * 2 + 1) & 3) * 16 + l15) * 4;

  const int nt = 32 - j;   // key tiles needed by the high q-tile (>= 17)

  // prologue: prefetch tiles 0 and 1 (each wave: 1 K + 1 V load per tile)
  gload_lds16(&k_sm[tid * 8], kgb);
  gload_lds16(&vt_sm[tid * 8], vgb);
  gload_lds16(&k_sm[4096 + tid * 8], kgb + (size_t)64 * N3);
  gload_lds16(&vt_sm[4096 + tid * 8], vgb + 64);

  int bt = 0;   // LDS buffer index of tile t (t mod 3)
  for (int t = 0; t < nt; t++) {
    // wait OWN tile-t staging; allow tile-(t+1)'s 2 loads to stay in flight
    if (t + 1 < nt) asm volatile("s_waitcnt vmcnt(2)" ::: "memory");
    else            asm volatile("s_waitcnt vmcnt(0)" ::: "memory");
    __builtin_amdgcn_s_barrier();   // all waves' tile-t staged; t-1 reads done
    __builtin_amdgcn_sched_barrier(0);
    if (t + 2 < nt) {               // prefetch tile t+2 into buffer (bt+2)%3
      const int b2 = (bt == 0) ? 2 : bt - 1;
      gload_lds16(&k_sm[b2 * 4096 + tid * 8], kgb + (size_t)(t + 2) * 64 * N3);
      gload_lds16(&vt_sm[b2 * 4096 + tid * 8], vgb + (t + 2) * 64);
    }
    const unsigned short* kb = &k_sm[bt * 4096];
    const unsigned short* vb = &vt_sm[bt * 4096];
    bt = (bt == 2) ? 0 : bt + 1;
    if (t * 64 > wrow0 + 15) continue;   // tile fully masked for this wave

    // S^T = K Q^T : D[m=key][n=qrow]; lane holds keys mb*16+quad*4+r, qrow=l15
    f32x4 s[4];
#pragma unroll
    for (int mb = 0; mb < 4; mb++) s[mb] = (f32x4){0.f, 0.f, 0.f, 0.f};
#pragma unroll
    for (int mb = 0; mb < 4; mb++) {
      const int ro = (mb * 16 + l15) * 64;
      bf16x8 kf0 = *(const bf16x8*)&kb[ro + ((quad ^ sw) << 3)];
      bf16x8 kf1 = *(const bf16x8*)&kb[ro + (((4 + quad) ^ sw) << 3)];
      s[mb] = __builtin_amdgcn_mfma_f32_16x16x32_bf16(kf0, qf[0], s[mb], 0, 0, 0);
      s[mb] = __builtin_amdgcn_mfma_f32_16x16x32_bf16(kf1, qf[1], s[mb], 0, 0, 0);
    }

    // P = exp2(S) (scale pre-folded); mask only when tile straddles diagonal
    if (t * 64 + 63 <= wrow0) {
#pragma unroll
      for (int mb = 0; mb < 4; mb++)
#pragma unroll
        for (int r = 0; r < 4; r++)
          s[mb][r] = exp2f(s[mb][r]);
    } else {
      const int kq0 = t * 64 + quad * 4;
#pragma unroll
      for (int mb = 0; mb < 4; mb++)
#pragma unroll
        for (int r = 0; r < 4; r++) {
          const float e = exp2f(s[mb][r]);
          s[mb][r] = (kq0 + mb * 16 + r <= qrow) ? e : 0.f;
        }
    }
#pragma unroll
    for (int mb = 0; mb < 4; mb++)
      lsum += (s[mb][0] + s[mb][1]) + (s[mb][2] + s[mb][3]);

    // pack to bf16 pairs: pk[mb][x] = keys (mb*16+quad*4+2x, +2x+1)
    int pk[4][2];
#pragma unroll
    for (int mb = 0; mb < 4; mb++) {
      const unsigned u0 = __float_as_uint(s[mb][0]) + 0x8000u;
      const unsigned u1 = __float_as_uint(s[mb][1]) + 0x8000u;
      const unsigned u2 = __float_as_uint(s[mb][2]) + 0x8000u;
      const unsigned u3 = __float_as_uint(s[mb][3]) + 0x8000u;
      pk[mb][0] = (int)__builtin_amdgcn_perm(u1, u0, 0x07060302u);
      pk[mb][1] = (int)__builtin_amdgcn_perm(u3, u2, 0x07060302u);
    }

    // O^T += V^T P^T : per K-step ks (32 keys) build P^T B-fragment
    const bool hi = quad >= 2;   // m_src = 2ks + (quad>>1)
#pragma unroll
    for (int ks = 0; ks < 2; ks++) {
      const int m0 = 2 * ks, m1 = m0 + 1;
      const int f0a = __builtin_amdgcn_ds_bpermute(addrA, pk[m0][0]);
      const int f0b = __builtin_amdgcn_ds_bpermute(addrA, pk[m1][0]);
      const int f1a = __builtin_amdgcn_ds_bpermute(addrA, pk[m0][1]);
      const int f1b = __builtin_amdgcn_ds_bpermute(addrA, pk[m1][1]);
      const int f2a = __builtin_amdgcn_ds_bpermute(addrB, pk[m0][0]);
      const int f2b = __builtin_amdgcn_ds_bpermute(addrB, pk[m1][0]);
      const int f3a = __builtin_amdgcn_ds_bpermute(addrB, pk[m0][1]);
      const int f3b = __builtin_amdgcn_ds_bpermute(addrB, pk[m1][1]);
      i32x4 fr;
      fr.x = hi ? f0b : f0a;
      fr.y = hi ? f1b : f1a;
      fr.z = hi ? f2b : f2a;
      fr.w = hi ? f3b : f3a;
      const bf16x8 pfrag = __builtin_bit_cast(bf16x8, fr);
#pragma unroll
      for (int mb = 0; mb < 4; mb++) {
        const int ro = (mb * 16 + l15) * 64;
        bf16x8 vf = *(const bf16x8*)&vb[ro + (((ks * 4 + quad) ^ sw) << 3)];
        o[mb] = __builtin_amdgcn_mfma_f32_16x16x32_bf16(vf, pfrag, o[mb], 0, 0, 0);
      }
    }
  }

  // drain any straggler staging writes before workgroup teardown
  asm volatile("s_waitcnt vmcnt(0)" ::: "memory");

  // normalize + write (O^T: lane has 4 consecutive d per mb for its qrow)
  float l = lsum;
  l += __shfl_xor(l, 16);
  l += __shfl_xor(l, 32);
  const float inv = 1.0f / l;
  const size_t grow = (size_t)(b * S_ + qrow);
#pragma unroll
  for (int mb = 0; mb < 4; mb++) {
    ushort4 w;
    w.x = f2bf(o[mb][0] * inv);
    w.y = f2bf(o[mb][1] * inv);
    w.z = f2bf(o[mb][2] * inv);
    w.w = f2bf(o[mb][3] * inv);
    *(ushort4*)&attnout[grow * DM + h * HD + mb * 16 + quad * 4] = w;
  }
}

// ---------------------------------------------------------------------------
extern "C" void kernel_launch(void* const* d_in, const int* in_sizes, int n_in,
                              void* d_out, int out_size, void* d_ws, size_t ws_size,
                              hipStream_t stream) {
  const float* query = (const float*)d_in[0];   // [4096][1024]
  const float* w_in  = (const float*)d_in[1];   // [1024][3072]
  const float* w_out = (const float*)d_in[2];   // [1024][1024]
  float* out = (float*)d_out;                   // [4096][1024] fp32

  char* ws = (char*)d_ws;
  unsigned short* qbf     = (unsigned short*)(ws);                 //  8 MB (dead after gemm1)
  unsigned short* vT      = (unsigned short*)(ws);                 //  8 MB (aliases qbf)
  unsigned short* w_in_t  = (unsigned short*)(ws + 8388608);       //  6 MB [3072][1024]
  unsigned short* w_out_t = (unsigned short*)(ws + 14680064);      //  2 MB [1024][1024]
  unsigned short* qkv     = (unsigned short*)(ws + 16777216);      // 24 MB [4096][3072]
  unsigned short* attn    = (unsigned short*)(ws + 41943040);      //  8 MB [4096][1024]

  // 1. convert query fp32 -> bf16
  f32_to_bf16_vec<<<dim3(M_ * DM / 1024), dim3(256), 0, stream>>>(
      (const float4*)query, qbf, M_ * DM / 4);
  // 2. transpose+convert weights; fold 0.125*log2e into W_in Q-columns
  transpose_f32_bf16<<<dim3(N3 / 32, DM / 32), dim3(32, 8), 0, stream>>>(
      w_in, w_in_t, DM, N3, DM, SCALE_LOG2E);
  transpose_f32_bf16<<<dim3(DM / 32, DM / 32), dim3(32, 8), 0, stream>>>(
      w_out, w_out_t, DM, DM, 0, 1.0f);
  // 3. qkv = query @ W_in   [4096][3072] bf16 (Q slice pre-scaled)
  gemm_abt<1><<<dim3(N3 / 128, M_ / 128), dim3(256), 0, stream>>>(qbf, w_in_t, qkv, M_, N3, DM);
  // 4. vT[b][h][d][s] from qkv V slice (qbf is dead now)
  transpose_v<<<dim3(DM / 32, M_ / 32), dim3(32, 8), 0, stream>>>(qkv, vT);
  // 5. fused causal attention -> attn [4096][1024] bf16
  attn_fused8<<<dim3(16, NH, B_), dim3(512), 0, stream>>>(qkv, vT, attn);
  // 6. out = attn @ W_out   [4096][1024] fp32
  gemm_abt<0><<<dim3(DM / 128, M_ / 128), dim3(256), 0, stream>>>(attn, w_out_t, out, M_, DM, DM);
}

// Round 7
// 204.146 us; speedup vs baseline: 1.1330x; 1.0214x over previous
//
#include <hip/hip_runtime.h>

// ---------------------------------------------------------------------------
// MultiHeadedAttention: B=2, S=2048, Dm=1024, H=16, hd=64
// R10: R9 staging (counted vmcnt, verified) + cross-tile software pipeline:
//  - PV shifted one tile back: iteration t runs QK^T+softmax(t) || PV(t-1)
//    as two INDEPENDENT dep-chains (pk registers carried across the barrier)
//    -> per-tile critical path ~max(S-chain, PV-chain) instead of their sum
//  - 4 LDS buffers (64KB): PV(t-1) reads buffer (t-1)%4; staging(t+2) writes
//    (t+2)%4 -- distinct; reads complete before barrier t+1 (lgkmcnt before
//    dependent MFMA), overwrite (tile t+3) issued after barrier t+1
//  - epilogue PV for the high-tile waves' last tile
//  - everything else identical to R4/R9: (j,31-j) pairing, 512 thr, 16x16x32
//    MFMA, ds_bpermute P-transpose, scale*log2e pre-folded into W_in
// ---------------------------------------------------------------------------

typedef __bf16 bf16x8 __attribute__((ext_vector_type(8)));
typedef float f32x4 __attribute__((ext_vector_type(4)));
typedef int i32x4 __attribute__((ext_vector_type(4)));

#define B_   2
#define S_   2048
#define DM   1024
#define NH   16
#define HD   64
#define N3   3072
#define M_   4096   // B_*S_

// 0.125 (1/sqrt(64)) * log2(e) -- folded into W_in Q-columns on host side
#define SCALE_LOG2E 0.180336884f

__device__ __forceinline__ unsigned short f2bf(float f) {
  unsigned int u = __float_as_uint(f);
  u += 0x7fffu + ((u >> 16) & 1u);   // round-to-nearest-even
  return (unsigned short)(u >> 16);
}

__device__ __forceinline__ void gload_lds16(void* lds, const void* g) {
  __builtin_amdgcn_global_load_lds(
      (__attribute__((address_space(1))) void*)g,
      (__attribute__((address_space(3))) void*)lds, 16, 0, 0);
}

// ---------------- fp32 -> bf16 elementwise (query) -------------------------
__global__ __launch_bounds__(256) void f32_to_bf16_vec(
    const float4* __restrict__ in, unsigned short* __restrict__ out, int n4) {
  int i = blockIdx.x * 256 + threadIdx.x;
  if (i < n4) {
    float4 v = in[i];
    ushort4 o;
    o.x = f2bf(v.x); o.y = f2bf(v.y); o.z = f2bf(v.z); o.w = f2bf(v.w);
    *(ushort4*)(&out[(size_t)i * 4]) = o;
  }
}

// ------- fp32 [R][C] -> bf16 [C][R] transpose (weights), row-scaled --------
__global__ __launch_bounds__(256) void transpose_f32_bf16(
    const float* __restrict__ in, unsigned short* __restrict__ out, int R, int C,
    int scale_rows, float scale) {
  __shared__ float tile[32][33];
  const int tx = threadIdx.x, ty = threadIdx.y;
  const int x = blockIdx.x * 32 + tx;
  const int y0 = blockIdx.y * 32;
#pragma unroll
  for (int j = 0; j < 32; j += 8)
    tile[ty + j][tx] = in[(size_t)(y0 + ty + j) * C + x];
  __syncthreads();
  const int ox = y0 + tx;
  const int oy0 = blockIdx.x * 32;
#pragma unroll
  for (int j = 0; j < 32; j += 8) {
    const int orow = oy0 + ty + j;
    float v = tile[tx][ty + j];
    if (orow < scale_rows) v *= scale;
    out[(size_t)orow * R + ox] = f2bf(v);
  }
}

// ---------------- V slice of qkv -> vT[b][h][d][s] (bf16) ------------------
__global__ __launch_bounds__(256) void transpose_v(
    const unsigned short* __restrict__ qkv, unsigned short* __restrict__ vT) {
  __shared__ unsigned short tile[32][33];
  const int tx = threadIdx.x, ty = threadIdx.y;
  const int c0 = blockIdx.x * 32;   // v-dim 0..1023
  const int r0 = blockIdx.y * 32;   // token 0..4095
#pragma unroll
  for (int j = 0; j < 32; j += 8)
    tile[ty + j][tx] = qkv[(size_t)(r0 + ty + j) * N3 + 2 * DM + c0 + tx];
  __syncthreads();
  const int b = r0 >> 11;
  const int srow = (r0 & 2047);
  const int head = c0 >> 6;
#pragma unroll
  for (int j = 0; j < 32; j += 8) {
    const int d = (c0 & 63) + ty + j;
    vT[(size_t)((b * NH + head) * HD + d) * S_ + srow + tx] = tile[tx][ty + j];
  }
}

// ---------------- GEMM: C[M][N] = A[M][K] @ Bt[N][K]^T ---------------------
template <int OUT_BF16>
__global__ __launch_bounds__(256) void gemm_abt(
    const unsigned short* __restrict__ A, const unsigned short* __restrict__ Bt,
    void* __restrict__ Cv, int M, int N, int K) {
  __shared__ __align__(16) unsigned short a_sm[128 * 32];
  __shared__ __align__(16) unsigned short b_sm[128 * 32];
  const int tid = threadIdx.x;
  const int lane = tid & 63, wave = tid >> 6;
  const int quad = lane >> 4, l15 = lane & 15;
  const int row0 = blockIdx.y * 128, col0 = blockIdx.x * 128;
  const int wm = (wave >> 1) * 64, wn = (wave & 1) * 64;

  f32x4 acc[4][4];
#pragma unroll
  for (int i = 0; i < 4; i++)
#pragma unroll
    for (int j = 0; j < 4; j++) acc[i][j] = (f32x4){0.f, 0.f, 0.f, 0.f};

  const int e0 = tid * 8;

  for (int k0 = 0; k0 < K; k0 += 32) {
    __syncthreads();
#pragma unroll
    for (int i = 0; i < 2; i++) {
      int e = e0 + i * 2048;
      int r = e >> 5, c = e & 31;
      gload_lds16(&a_sm[e], &A[(size_t)(row0 + r) * K + k0 + c]);
      gload_lds16(&b_sm[e], &Bt[(size_t)(col0 + r) * K + k0 + c]);
    }
    __syncthreads();

    bf16x8 af[4], bfb[4];
#pragma unroll
    for (int i = 0; i < 4; i++) {
      af[i]  = *(const bf16x8*)&a_sm[(wm + i * 16 + l15) * 32 + quad * 8];
      bfb[i] = *(const bf16x8*)&b_sm[(wn + i * 16 + l15) * 32 + quad * 8];
    }
#pragma unroll
    for (int i = 0; i < 4; i++)
#pragma unroll
      for (int j = 0; j < 4; j++)
        acc[i][j] = __builtin_amdgcn_mfma_f32_16x16x32_bf16(af[i], bfb[j], acc[i][j], 0, 0, 0);
  }

#pragma unroll
  for (int i = 0; i < 4; i++) {
#pragma unroll
    for (int j = 0; j < 4; j++) {
#pragma unroll
      for (int r = 0; r < 4; r++) {
        const int row = row0 + wm + i * 16 + quad * 4 + r;
        const int col = col0 + wn + j * 16 + l15;
        const float v = acc[i][j][r];
        if (OUT_BF16)
          ((unsigned short*)Cv)[(size_t)row * N + col] = f2bf(v);
        else
          ((float*)Cv)[(size_t)row * N + col] = v;
      }
    }
  }
}

// ---------------- fused causal attention v9 --------------------------------
// grid (16, NH, B), 512 threads (8 waves).
// Block j owns q-tiles j (waves 0-3) and 31-j (waves 4-7), 64 rows each.
// 4-deep LDS buffers, prefetch distance 2, counted vmcnt + raw s_barrier.
// Software pipeline: iteration t = QK^T+softmax(t) || PV(t-1).
__global__ __launch_bounds__(512, 4) void attn_fused9(
    const unsigned short* __restrict__ qkv,
    const unsigned short* __restrict__ vT,
    unsigned short* __restrict__ attnout) {
  const int h = blockIdx.y, b = blockIdx.z;
  const int j = blockIdx.x;                     // pair index 0..15
  const int tid = threadIdx.x;
  const int lane = tid & 63, wave = tid >> 6;   // wave 0..7
  const int quad = lane >> 4, l15 = lane & 15;
  const int sw = l15 & 7;

  __shared__ __align__(16) unsigned short k_sm[4 * 4096];   // [buf][64 keys][64 d]
  __shared__ __align__(16) unsigned short vt_sm[4 * 4096];  // [buf][64 d][64 keys]

  // wave 0..3 -> low q-tile (rows j*64 ..); wave 4..7 -> high tile ((31-j)*64 ..)
  const int wrow0 = (wave < 4) ? (j * 64 + wave * 16)
                               : ((31 - j) * 64 + (wave - 4) * 16);
  const int qrow = wrow0 + l15;            // this lane's q row (seq-local)

  // Q fragment (B-operand for S^T, A/B layouts are lane-symmetric)
  bf16x8 qf[2];
  {
    const unsigned short* qp = qkv + (size_t)(b * S_ + qrow) * N3 + h * HD + quad * 8;
    qf[0] = *(const bf16x8*)qp;
    qf[1] = *(const bf16x8*)(qp + 32);
  }

  f32x4 o[4];   // O^T accumulator: d = mb*16+quad*4+r, col = qrow
#pragma unroll
  for (int n = 0; n < 4; n++) o[n] = (f32x4){0.f, 0.f, 0.f, 0.f};
  float lsum = 0.f;

  // staging: thread -> (row r0s, phys chunk tid&7); phys chunk holds logical
  // chunk (tid&7)^(r0s&7)  (XOR swizzle, conflict-free b128 reads)
  const int r0s = tid >> 3;                       // 0..63
  const int gch = ((tid & 7) ^ (r0s & 7)) * 8;
  const unsigned short* kgb = qkv + (size_t)(b * S_ + r0s) * N3 + DM + h * HD + gch;
  const unsigned short* vgb = vT + (size_t)((b * NH + h) * HD + r0s) * S_ + gch;

  // bpermute pull addresses (byte addr = src_lane*4), quad-dim transpose
  const int addrA = (((quad * 2) & 3) * 16 + l15) * 4;
  const int addrB = (((quad * 2 + 1) & 3) * 16 + l15) * 4;

  const int nt = 32 - j;   // key tiles needed by the high q-tile (>= 17)

  // carried pipeline state: packed P of the previous tile + its V buffer
  int pk[4][2];
  const unsigned short* vbp = &vt_sm[0];
  const bool hi = quad >= 2;   // m_src = 2ks + (quad>>1)

  // PV step for the previous tile (reads pk + vbp, accumulates o[])
  auto PV = [&]() {
#pragma unroll
    for (int ks = 0; ks < 2; ks++) {
      const int m0 = 2 * ks, m1 = m0 + 1;
      const int f0a = __builtin_amdgcn_ds_bpermute(addrA, pk[m0][0]);
      const int f0b = __builtin_amdgcn_ds_bpermute(addrA, pk[m1][0]);
      const int f1a = __builtin_amdgcn_ds_bpermute(addrA, pk[m0][1]);
      const int f1b = __builtin_amdgcn_ds_bpermute(addrA, pk[m1][1]);
      const int f2a = __builtin_amdgcn_ds_bpermute(addrB, pk[m0][0]);
      const int f2b = __builtin_amdgcn_ds_bpermute(addrB, pk[m1][0]);
      const int f3a = __builtin_amdgcn_ds_bpermute(addrB, pk[m0][1]);
      const int f3b = __builtin_amdgcn_ds_bpermute(addrB, pk[m1][1]);
      i32x4 fr;
      fr.x = hi ? f0b : f0a;
      fr.y = hi ? f1b : f1a;
      fr.z = hi ? f2b : f2a;
      fr.w = hi ? f3b : f3a;
      const bf16x8 pfrag = __builtin_bit_cast(bf16x8, fr);
#pragma unroll
      for (int mb = 0; mb < 4; mb++) {
        const int ro = (mb * 16 + l15) * 64;
        bf16x8 vf = *(const bf16x8*)&vbp[ro + (((ks * 4 + quad) ^ sw) << 3)];
        o[mb] = __builtin_amdgcn_mfma_f32_16x16x32_bf16(vf, pfrag, o[mb], 0, 0, 0);
      }
    }
  };

  // prologue: prefetch tiles 0 and 1 (each wave: 1 K + 1 V load per tile)
  gload_lds16(&k_sm[tid * 8], kgb);
  gload_lds16(&vt_sm[tid * 8], vgb);
  gload_lds16(&k_sm[4096 + tid * 8], kgb + (size_t)64 * N3);
  gload_lds16(&vt_sm[4096 + tid * 8], vgb + 64);

  for (int t = 0; t < nt; t++) {
    // wait OWN tile-t staging; tile-(t+1)'s 2 loads may stay in flight
    if (t + 1 < nt) asm volatile("s_waitcnt vmcnt(2)" ::: "memory");
    else            asm volatile("s_waitcnt vmcnt(0)" ::: "memory");
    __builtin_amdgcn_s_barrier();   // tile t staged everywhere; t-2 reads done
    __builtin_amdgcn_sched_barrier(0);
    if (t + 2 < nt) {               // prefetch tile t+2 into buffer (t+2)%4
      const int b2 = (t + 2) & 3;
      gload_lds16(&k_sm[b2 * 4096 + tid * 8], kgb + (size_t)(t + 2) * 64 * N3);
      gload_lds16(&vt_sm[b2 * 4096 + tid * 8], vgb + (t + 2) * 64);
    }
    const unsigned short* kb = &k_sm[(t & 3) * 4096];
    const unsigned short* vb = &vt_sm[(t & 3) * 4096];

    // ---- stream B: PV of tile t-1 (independent of stream A) ----
    if (t >= 1 && (t - 1) * 64 <= wrow0 + 15) PV();

    // ---- stream A: S^T(t) + softmax + pack ----
    if (t * 64 <= wrow0 + 15) {
      f32x4 s[4];
#pragma unroll
      for (int mb = 0; mb < 4; mb++) s[mb] = (f32x4){0.f, 0.f, 0.f, 0.f};
#pragma unroll
      for (int mb = 0; mb < 4; mb++) {
        const int ro = (mb * 16 + l15) * 64;
        bf16x8 kf0 = *(const bf16x8*)&kb[ro + ((quad ^ sw) << 3)];
        bf16x8 kf1 = *(const bf16x8*)&kb[ro + (((4 + quad) ^ sw) << 3)];
        s[mb] = __builtin_amdgcn_mfma_f32_16x16x32_bf16(kf0, qf[0], s[mb], 0, 0, 0);
        s[mb] = __builtin_amdgcn_mfma_f32_16x16x32_bf16(kf1, qf[1], s[mb], 0, 0, 0);
      }

      // P = exp2(S) (scale pre-folded); mask only on the diagonal tile
      if (t * 64 + 63 <= wrow0) {
#pragma unroll
        for (int mb = 0; mb < 4; mb++)
#pragma unroll
          for (int r = 0; r < 4; r++)
            s[mb][r] = exp2f(s[mb][r]);
      } else {
        const int kq0 = t * 64 + quad * 4;
#pragma unroll
        for (int mb = 0; mb < 4; mb++)
#pragma unroll
          for (int r = 0; r < 4; r++) {
            const float e = exp2f(s[mb][r]);
            s[mb][r] = (kq0 + mb * 16 + r <= qrow) ? e : 0.f;
          }
      }
#pragma unroll
      for (int mb = 0; mb < 4; mb++)
        lsum += (s[mb][0] + s[mb][1]) + (s[mb][2] + s[mb][3]);

      // pack to bf16 pairs: pk[mb][x] = keys (mb*16+quad*4+2x, +2x+1)
#pragma unroll
      for (int mb = 0; mb < 4; mb++) {
        const unsigned u0 = __float_as_uint(s[mb][0]) + 0x8000u;
        const unsigned u1 = __float_as_uint(s[mb][1]) + 0x8000u;
        const unsigned u2 = __float_as_uint(s[mb][2]) + 0x8000u;
        const unsigned u3 = __float_as_uint(s[mb][3]) + 0x8000u;
        pk[mb][0] = (int)__builtin_amdgcn_perm(u1, u0, 0x07060302u);
        pk[mb][1] = (int)__builtin_amdgcn_perm(u3, u2, 0x07060302u);
      }
      vbp = vb;   // PV(t) runs next iteration (or in the epilogue)
    }
  }

  // epilogue PV: high-tile waves' last tile (nt-1) was packed, not consumed
  if ((nt - 1) * 64 <= wrow0 + 15) PV();

  // drain any straggler staging writes before workgroup teardown
  asm volatile("s_waitcnt vmcnt(0)" ::: "memory");

  // normalize + write (O^T: lane has 4 consecutive d per mb for its qrow)
  float l = lsum;
  l += __shfl_xor(l, 16);
  l += __shfl_xor(l, 32);
  const float inv = 1.0f / l;
  const size_t grow = (size_t)(b * S_ + qrow);
#pragma unroll
  for (int mb = 0; mb < 4; mb++) {
    ushort4 w;
    w.x = f2bf(o[mb][0] * inv);
    w.y = f2bf(o[mb][1] * inv);
    w.z = f2bf(o[mb][2] * inv);
    w.w = f2bf(o[mb][3] * inv);
    *(ushort4*)&attnout[grow * DM + h * HD + mb * 16 + quad * 4] = w;
  }
}

// ---------------------------------------------------------------------------
extern "C" void kernel_launch(void* const* d_in, const int* in_sizes, int n_in,
                              void* d_out, int out_size, void* d_ws, size_t ws_size,
                              hipStream_t stream) {
  const float* query = (const float*)d_in[0];   // [4096][1024]
  const float* w_in  = (const float*)d_in[1];   // [1024][3072]
  const float* w_out = (const float*)d_in[2];   // [1024][1024]
  float* out = (float*)d_out;                   // [4096][1024] fp32

  char* ws = (char*)d_ws;
  unsigned short* qbf     = (unsigned short*)(ws);                 //  8 MB (dead after gemm1)
  unsigned short* vT      = (unsigned short*)(ws);                 //  8 MB (aliases qbf)
  unsigned short* w_in_t  = (unsigned short*)(ws + 8388608);       //  6 MB [3072][1024]
  unsigned short* w_out_t = (unsigned short*)(ws + 14680064);      //  2 MB [1024][1024]
  unsigned short* qkv     = (unsigned short*)(ws + 16777216);      // 24 MB [4096][3072]
  unsigned short* attn    = (unsigned short*)(ws + 41943040);      //  8 MB [4096][1024]

  // 1. convert query fp32 -> bf16
  f32_to_bf16_vec<<<dim3(M_ * DM / 1024), dim3(256), 0, stream>>>(
      (const float4*)query, qbf, M_ * DM / 4);
  // 2. transpose+convert weights; fold 0.125*log2e into W_in Q-columns
  transpose_f32_bf16<<<dim3(N3 / 32, DM / 32), dim3(32, 8), 0, stream>>>(
      w_in, w_in_t, DM, N3, DM, SCALE_LOG2E);
  transpose_f32_bf16<<<dim3(DM / 32, DM / 32), dim3(32, 8), 0, stream>>>(
      w_out, w_out_t, DM, DM, 0, 1.0f);
  // 3. qkv = query @ W_in   [4096][3072] bf16 (Q slice pre-scaled)
  gemm_abt<1><<<dim3(N3 / 128, M_ / 128), dim3(256), 0, stream>>>(qbf, w_in_t, qkv, M_, N3, DM);
  // 4. vT[b][h][d][s] from qkv V slice (qbf is dead now)
  transpose_v<<<dim3(DM / 32, M_ / 32), dim3(32, 8), 0, stream>>>(qkv, vT);
  // 5. fused causal attention -> attn [4096][1024] bf16
  attn_fused9<<<dim3(16, NH, B_), dim3(512), 0, stream>>>(qkv, vT, attn);
  // 6. out = attn @ W_out   [4096][1024] fp32
  gemm_abt<0><<<dim3(DM / 128, M_ / 128), dim3(256), 0, stream>>>(attn, w_out_t, out, M_, DM, DM);
}